// Round 1
// 334.851 us; speedup vs baseline: 1.0371x; 1.0371x over previous
//
#include <hip/hip_runtime.h>
#include <hip/hip_bf16.h>

#define DEV __device__ __forceinline__

typedef short bf16x8 __attribute__((ext_vector_type(8)));
typedef float f32x4 __attribute__((ext_vector_type(4)));

static constexpr int BATCH  = 2;
static constexpr int SEQ    = 1024;
static constexpr int DMODEL = 1024;
static constexpr int DINNER = 2048;
static constexpr int DSTATE = 64;
static constexpr int NH     = 32;
static constexpr int HD     = 64;
static constexpr int CONVD  = 2176;
static constexpr int DPROJ  = 4256;
static constexpr int MROWS  = BATCH * SEQ;   // 2048
static constexpr int NCHUNK = 16;
static constexpr int QC     = 64;

// ---- workspace layout (bytes) ---- peak 74.8 MB (proven)
static constexpr size_t OFF_ZX = 0;                                  // bf16 [4096][4256]
static constexpr size_t OFF_XS = OFF_ZX + (size_t)2*MROWS*DPROJ*2;   // bf16 [4096][2048]; xbf pre-conv, xs after, yn after ssd
static constexpr size_t OFF_BB = OFF_XS + (size_t)2*MROWS*DINNER*2;  // f32 [4096][64]
static constexpr size_t OFF_CC = OFF_BB + (size_t)2*MROWS*DSTATE*4;  // f32 [4096][64]
static constexpr size_t OFF_DT = OFF_CC + (size_t)2*MROWS*DSTATE*4;  // f32 [4][32][1024] dt
static constexpr size_t OFF_DA = OFF_DT + (size_t)2*MROWS*NH*4;      // f32 [4][32][1024] ldA
static constexpr size_t OFF_DR = OFF_DA + (size_t)2*MROWS*NH*4;      // f32 [4096][32] raw dt spill
// CS region (16.8 MB), time-shared:
//  (a) bf16 in_proj weights [2][4256][1024] until gemm0
//  (b) chunk states [128][16][64][64] until ssd
//  (c) wo (bf16 [2][1024][2048], 8.4MB) + wp (bf16 [1024][2048], 4.2MB) after ssd
static constexpr size_t OFF_CS = OFF_DR + (size_t)2*MROWS*NH*4;
static constexpr size_t OFF_WO = OFF_CS;
static constexpr size_t OFF_WP = OFF_CS + (size_t)2*DMODEL*DINNER*2;
// aliased into zx (dead after grms):
static constexpr size_t OFF_DD = 0;                                  // bf16 [2048][2048] packed dir outs
static constexpr size_t OFF_H  = OFF_DD + (size_t)MROWS*2*DMODEL;    // f32 [2048][1024]

DEV float b2f(ushort u) {
    union { unsigned int i; float f; } v;
    v.i = ((unsigned int)u) << 16;
    return v.f;
}
DEV ushort f2b(float f) {
    union { float f; unsigned int u; } v;
    v.f = f;
    unsigned int r = 0x7FFFu + ((v.u >> 16) & 1u);
    return (ushort)((v.u + r) >> 16);
}
DEV bf16x8 pack8(float4 a, float4 b) {
    bf16x8 r;
    r[0] = (short)f2b(a.x); r[1] = (short)f2b(a.y);
    r[2] = (short)f2b(a.z); r[3] = (short)f2b(a.w);
    r[4] = (short)f2b(b.x); r[5] = (short)f2b(b.y);
    r[6] = (short)f2b(b.z); r[7] = (short)f2b(b.w);
    return r;
}
DEV void gll16(const ushort* g, ushort* l) {
    __builtin_amdgcn_global_load_lds(
        (const __attribute__((address_space(1))) unsigned int*)g,
        (__attribute__((address_space(3))) unsigned int*)l, 16, 0, 0);
}
// XCD-locality remap for 128-id grids (4 dirb x 32 h): each XCD owns one
// dirb and a 16-h slice -> shared xs/Bq/Cq rows stay in that XCD's L2.
DEV int idmap128(int bx) {
    int x8 = bx & 7, g = bx >> 3;          // g in 0..15
    return (x8 & 3) * 32 + (x8 >> 2) * 16 + g;
}

// ---------------------------------------------------------------------------
// cvt3: three fp32->bf16 conversions in one launch (rows of 1024 floats).
// ---------------------------------------------------------------------------
__global__ __launch_bounds__(256) void cvt3_k(
    const float* __restrict__ s0, const float* __restrict__ s1,
    const float* __restrict__ s2,
    ushort* __restrict__ d0, ushort* __restrict__ d1, ushort* __restrict__ d2,
    int b0, int b1)
{
    int blk = blockIdx.x;
    const float* s; ushort* d; size_t off;
    if (blk < b0)            { s = s0; d = d0; off = (size_t)blk * 1024; }
    else if (blk < b0 + b1)  { s = s1; d = d1; off = (size_t)(blk - b0) * 1024; }
    else                     { s = s2; d = d2; off = (size_t)(blk - b0 - b1) * 1024; }
    size_t i = off + threadIdx.x * 4;
    float4 f = *(const float4*)(s + i);
    ushort4 u;
    u.x = f2b(f.x); u.y = f2b(f.y); u.z = f2b(f.z); u.w = f2b(f.w);
    *(ushort4*)(d + i) = u;
}

// ---------------------------------------------------------------------------
// gemm_in_k: in_proj GEMM. BM=256, BN=128, BK=64, 512 threads (8 waves as
// 4M x 2N, wave tile 64x64 -- identical inner body to the proven BN=128
// path). Staged bytes/FLOP drop 28% vs BM=128 and barriers per FLOP halve;
// LDS = 48KB -> ~2 blocks/CU.  A-rows carry the dir-flip remap; cols >= N
// clamped on load, skipped on store; dt tail spilled to f32.
// Generalized XOR swizzle: LDS[row][slot] holds global colgroup
// slot ^ (row & 7) (16B groups) -> conflict-free ds_read_b128.
// ---------------------------------------------------------------------------
__global__ __launch_bounds__(512) void gemm_in_k(
    const ushort* __restrict__ A, const ushort* __restrict__ W,
    size_t wstride, ushort* __restrict__ outp, float* __restrict__ dtraw,
    int N, int K)
{
    constexpr int BM = 256;
    constexpr int BN = 128;
    constexpr int BK = 64;
    constexpr int NSL = BK / 8;          // 8 16B slots per LDS row
    constexpr int RPG = 64 / NSL;        // 8 rows per gll group
    constexpr int NAG = BM / RPG / 8;    // 4 A gll groups per wave (8 waves)
    constexpr int NBG = BN / RPG / 8;    // 2 B gll groups per wave
    __shared__ ushort As[BM * BK];       // 32 KB
    __shared__ ushort Bs[BN * BK];       // 16 KB
    const int tid = threadIdx.x;
    const int wave = tid >> 6, lane = tid & 63;
    const int quad = lane >> 4, l16 = lane & 15;
    const int bxu = (int)((blockIdx.x + 2 * blockIdx.y) % gridDim.x);
    const int bn = bxu * BN, bm = blockIdx.y * BM;
    const int dir = blockIdx.z;
    const ushort* Wd = W + (size_t)dir * wstride;
    const int wmoff = (wave >> 1) * 64;
    const int wnoff = (wave & 1) * 64;

    const int lrow = lane / NSL, lslot = lane % NSL;
    const ushort* aga[NAG];
    ushort* ald[NAG];
    #pragma unroll
    for (int t = 0; t < NAG; t++) {
        int li = wave * NAG + t;          // 0..31
        int absr = li * RPG + lrow;       // 0..255
        int m = bm + absr;                // per-dir row, 0..2047
        int b = m >> 10, l = m & 1023;
        int ls = dir ? (1023 - l) : l;
        size_t rowidx = (size_t)((b << 10) + ls);
        aga[t] = A + rowidx * K + (lslot ^ (absr & 7)) * 8;
        ald[t] = &As[li * 512];
    }
    const ushort* bga[NBG];
    ushort* bld[NBG];
    #pragma unroll
    for (int t = 0; t < NBG; t++) {
        int li = wave * NBG + t;          // 0..15
        int absr = li * RPG + lrow;       // 0..127
        int n = bn + absr;
        if (n >= N) n = N - 1;            // clamp; cols >= N discarded
        bga[t] = Wd + (size_t)n * K + (lslot ^ (absr & 7)) * 8;
        bld[t] = &Bs[li * 512];
    }

    f32x4 acc[4][4] = {};

    for (int k0 = 0; k0 < K; k0 += BK) {
        #pragma unroll
        for (int t = 0; t < NAG; t++) gll16(aga[t] + k0, ald[t]);
        #pragma unroll
        for (int t = 0; t < NBG; t++) gll16(bga[t] + k0, bld[t]);
        __syncthreads();

        #pragma unroll
        for (int kt = 0; kt < 2; kt++) {
            const int rs = (((kt * 4 + quad) ^ (l16 & 7))) * 8;
            bf16x8 af[4], bfr[4];
            #pragma unroll
            for (int mt = 0; mt < 4; mt++)
                af[mt] = *(const bf16x8*)&As[(wmoff + mt * 16 + l16) * BK + rs];
            #pragma unroll
            for (int nt = 0; nt < 4; nt++)
                bfr[nt] = *(const bf16x8*)&Bs[(wnoff + nt * 16 + l16) * BK + rs];
            #pragma unroll
            for (int mt = 0; mt < 4; mt++)
                #pragma unroll
                for (int nt = 0; nt < 4; nt++)
                    acc[mt][nt] = __builtin_amdgcn_mfma_f32_16x16x32_bf16(
                        af[mt], bfr[nt], acc[mt][nt], 0, 0, 0);
        }
        __syncthreads();
    }

    // epilogue: C/D layout row=quad*4+j, col=l16
    #pragma unroll
    for (int mt = 0; mt < 4; mt++) {
        #pragma unroll
        for (int nt = 0; nt < 4; nt++) {
            #pragma unroll
            for (int j = 0; j < 4; j++) {
                int row = bm + wmoff + mt * 16 + quad * 4 + j;   // 0..2047
                int col = bn + wnoff + nt * 16 + l16;
                if (col >= N) continue;
                float v = acc[mt][nt][j];
                outp[(size_t)(dir * MROWS + row) * DPROJ + col] = f2b(v);
                if (col >= 4224)
                    dtraw[(size_t)(dir * MROWS + row) * NH + (col - 4224)] = v;
            }
        }
    }
}

// ---------------------------------------------------------------------------
// GEMM: C[m][n] = sum_k A[m][k]*W[n][k], all bf16, global_load_lds width-16
// staging, BM=128, BN ∈ {64,128}, BK ∈ {64,128}.
// Generalized XOR swizzle: LDS[row][slot] holds global colgroup
// slot ^ (row mod BK/8) (16 B groups) -> conflict-free ds_read_b128.
// (MODE 0 retired to gemm_in_k; MODE 1 = out_proj pack, MODE 2 = final proj.)
// ---------------------------------------------------------------------------
template<int MODE, int BN, int BK>
__global__ __launch_bounds__(256) void gemm_k(
    const ushort* __restrict__ A, const ushort* __restrict__ W,
    size_t wstride, void* __restrict__ outp, const float* __restrict__ resid,
    const float* __restrict__ bias, float* __restrict__ dtraw,
    int N, int K)
{
    constexpr int BM = 128;
    constexpr int MT = (BN == 128) ? 4 : 2;
    constexpr int NSL = BK / 8;          // 16B slots per LDS row
    constexpr int RPG = 64 / NSL;        // rows per gll group
    constexpr int NAG = BM / RPG / 4;    // A gll groups per wave
    constexpr int NBG = BN / RPG / 4;    // B gll groups per wave
    __shared__ ushort As[BM * BK];
    __shared__ ushort Bs[BN * BK];
    const int tid = threadIdx.x;
    const int wave = tid >> 6, lane = tid & 63;
    const int quad = lane >> 4, l16 = lane & 15;
    const int bxu = (MODE == 0)
        ? (int)((blockIdx.x + 2 * blockIdx.y) % gridDim.x) : (int)blockIdx.x;
    const int bn = bxu * BN, bm = blockIdx.y * BM;
    const int dir = blockIdx.z;
    const ushort* Wd = W + (size_t)dir * wstride;
    const int wmoff = (BN == 128) ? (wave >> 1) * 64 : wave * 32;
    const int wnoff = (BN == 128) ? (wave & 1) * 64 : 0;

    const int lrow = lane / NSL, lslot = lane % NSL;
    const ushort* aga[NAG];
    ushort* ald[NAG];
    #pragma unroll
    for (int t = 0; t < NAG; t++) {
        int li = wave * NAG + t;
        int absr = li * RPG + lrow;
        int m = bm + absr;
        size_t rowidx;
        if (MODE == 0) {
            int b = m >> 10, l = m & 1023;
            int ls = dir ? (1023 - l) : l;
            rowidx = (size_t)((b << 10) + ls);
        } else if (MODE == 1) {
            rowidx = (size_t)(dir * MROWS + m);
        } else {
            rowidx = (size_t)m;
        }
        aga[t] = A + rowidx * K + (lslot ^ (absr % NSL)) * 8;
        ald[t] = &As[li * 512];
    }
    const ushort* bga[NBG];
    ushort* bld[NBG];
    #pragma unroll
    for (int t = 0; t < NBG; t++) {
        int li = wave * NBG + t;
        int absr = li * RPG + lrow;
        int n = bn + absr;
        if (n >= N) n = N - 1;            // clamp; cols >= N discarded
        bga[t] = Wd + (size_t)n * K + (lslot ^ (absr % NSL)) * 8;
        bld[t] = &Bs[li * 512];
    }

    f32x4 acc[MT][4] = {};

    for (int k0 = 0; k0 < K; k0 += BK) {
        #pragma unroll
        for (int t = 0; t < NAG; t++) gll16(aga[t] + k0, ald[t]);
        #pragma unroll
        for (int t = 0; t < NBG; t++) gll16(bga[t] + k0, bld[t]);
        __syncthreads();

        #pragma unroll
        for (int kt = 0; kt < BK / 32; kt++) {
            const int rs = (((kt * 4 + quad) ^ (l16 % NSL))) * 8;
            bf16x8 af[MT], bfr[4];
            #pragma unroll
            for (int mt = 0; mt < MT; mt++)
                af[mt] = *(const bf16x8*)&As[(wmoff + mt * 16 + l16) * BK + rs];
            #pragma unroll
            for (int nt = 0; nt < 4; nt++)
                bfr[nt] = *(const bf16x8*)&Bs[(wnoff + nt * 16 + l16) * BK + rs];
            #pragma unroll
            for (int mt = 0; mt < MT; mt++)
                #pragma unroll
                for (int nt = 0; nt < 4; nt++)
                    acc[mt][nt] = __builtin_amdgcn_mfma_f32_16x16x32_bf16(
                        af[mt], bfr[nt], acc[mt][nt], 0, 0, 0);
        }
        __syncthreads();
    }

    // epilogue: C/D layout row=quad*4+j, col=l16
    #pragma unroll
    for (int mt = 0; mt < MT; mt++) {
        #pragma unroll
        for (int nt = 0; nt < 4; nt++) {
            #pragma unroll
            for (int j = 0; j < 4; j++) {
                int row = bm + wmoff + mt * 16 + quad * 4 + j;
                int col = bn + wnoff + nt * 16 + l16;
                if (col >= N) continue;
                float v = acc[mt][nt][j];
                if (MODE == 0) {
                    ((ushort*)outp)[(size_t)(dir * MROWS + row) * DPROJ + col] = f2b(v);
                    if (col >= 4224)
                        dtraw[(size_t)(dir * MROWS + row) * NH + (col - 4224)] = v;
                } else if (MODE == 1) {
                    int mr = dir ? ((row & 1024) | (1023 - (row & 1023))) : row;
                    ((ushort*)outp)[(size_t)mr * (2 * DMODEL) + dir * DMODEL + col] = f2b(v);
                } else {
                    float r = resid[(size_t)row * DMODEL + col] + bias[col];
                    ((float*)outp)[(size_t)row * DMODEL + col] = v + r;
                }
            }
        }
    }
}

// ---------------------------------------------------------------------------
// causal depthwise conv(width 4) + bias + SiLU — vectorized 4 chans/thread.
// Block remap: XCD owns a contiguous 512-row range so conv taps (rows
// id-3..id) stay L2-hot. dt = softplus(raw+bias); ldA = A*dt.
// dt/ldA TRANSPOSED: [dirb*32+h][l]
// ---------------------------------------------------------------------------
__global__ __launch_bounds__(256) void conv_k(
    const ushort* __restrict__ zx, const float* __restrict__ dtr,
    const float* __restrict__ cw0, const float* __restrict__ cb0,
    const float* __restrict__ cw1, const float* __restrict__ cb1,
    const float* __restrict__ dtb0, const float* __restrict__ al0,
    const float* __restrict__ dtb1, const float* __restrict__ al1,
    ushort* __restrict__ xs, float* __restrict__ Bq, float* __restrict__ Cq,
    float* __restrict__ dtq, float* __restrict__ ldq)
{
    int bx = blockIdx.x;
    int id = (bx & 7) * 512 + (bx >> 3);   // XCD-contiguous row ranges
    int dir = id >> 11;
    int m = id & 2047;
    int l = m & 1023;
    const float* cw = dir ? cw1 : cw0;
    const float* cb = dir ? cb1 : cb0;
    int tid = threadIdx.x;

    for (int c = tid * 4; c < CONVD; c += 1024) {
        float4 cbv = *(const float4*)&cb[c];
        float acc[4] = { cbv.x, cbv.y, cbv.z, cbv.w };
        #pragma unroll
        for (int t = 0; t < 4; t++) {
            int ls = l - 3 + t;
            if (ls >= 0) {
                float4 wv = *(const float4*)&cw[t * CONVD + c];
                ushort4 xv = *(const ushort4*)&zx[(size_t)(id - l + ls) * DPROJ + 2048 + c];
                acc[0] += wv.x * b2f(xv.x);
                acc[1] += wv.y * b2f(xv.y);
                acc[2] += wv.z * b2f(xv.z);
                acc[3] += wv.w * b2f(xv.w);
            }
        }
        float v[4];
        #pragma unroll
        for (int i = 0; i < 4; i++) v[i] = acc[i] / (1.f + expf(-acc[i]));
        if (c < DINNER) {
            ushort4 u;
            u.x = f2b(v[0]); u.y = f2b(v[1]); u.z = f2b(v[2]); u.w = f2b(v[3]);
            *(ushort4*)&xs[(size_t)id * DINNER + c] = u;
        } else if (c < DINNER + DSTATE) {
            *(float4*)&Bq[(size_t)id * DSTATE + (c - DINNER)] =
                make_float4(v[0], v[1], v[2], v[3]);
        } else {
            *(float4*)&Cq[(size_t)id * DSTATE + (c - DINNER - DSTATE)] =
                make_float4(v[0], v[1], v[2], v[3]);
        }
    }
    if (tid < NH) {
        const float* dtb = dir ? dtb1 : dtb0;
        const float* al  = dir ? al1 : al0;
        float raw = dtr[(size_t)id * NH + tid] + dtb[tid];
        float dt = raw > 20.f ? raw : log1pf(expf(raw));
        float ldA = -expf(al[tid]) * dt;
        int dirb = id >> 10;
        dtq[(size_t)(dirb * NH + tid) * SEQ + l] = dt;
        ldq[(size_t)(dirb * NH + tid) * SEQ + l] = ldA;
    }
}

// ---------------------------------------------------------------------------
// states_k: chunk-local end state via MFMA. Block remap via idmap128.
// ---------------------------------------------------------------------------
__global__ __launch_bounds__(256) void states_k(
    const float* __restrict__ Bq, const float* __restrict__ dtT,
    const float* __restrict__ ldT, const ushort* __restrict__ xsq,
    ushort* __restrict__ cs)
{
    int id = idmap128(blockIdx.x);
    int h = id & 31;
    int c = blockIdx.y;
    int tid = threadIdx.x;
    int wave = tid >> 6, lane = tid & 63;
    int quad = lane >> 4;
    int base = (id >> 5) << 10;
    int l0 = c * QC;

    __shared__ float wsh[QC];
    __shared__ ushort Xw[64][80];
    __shared__ ushort Bt[64][72];

    if (tid < 64) {
        float ld = ldT[(size_t)id * SEQ + l0 + tid];
        #pragma unroll
        for (int st = 1; st < 64; st <<= 1) {
            float o = __shfl_up(ld, st);
            if (tid >= st) ld += o;
        }
        float tot = __shfl(ld, 63);
        wsh[tid] = dtT[(size_t)id * SEQ + l0 + tid] * expf(tot - ld);
    }
    __syncthreads();

    {
        int j = tid >> 2, p0 = (tid & 3) * 16;
        float wj = wsh[j];
        const ushort* xrow = xsq + (size_t)(base + l0 + j) * DINNER + h * HD + p0;
        #pragma unroll
        for (int q = 0; q < 4; q++) {
            ushort4 xv = *(const ushort4*)(xrow + q * 4);
            Xw[p0 + q * 4 + 0][j] = f2b(b2f(xv.x) * wj);
            Xw[p0 + q * 4 + 1][j] = f2b(b2f(xv.y) * wj);
            Xw[p0 + q * 4 + 2][j] = f2b(b2f(xv.z) * wj);
            Xw[p0 + q * 4 + 3][j] = f2b(b2f(xv.w) * wj);
        }
        int j2 = lane, ng = wave * 16;
        const float* brow = Bq + (size_t)(base + l0 + j2) * DSTATE + ng;
        #pragma unroll
        for (int q = 0; q < 4; q++) {
            float4 f = *(const float4*)(brow + q * 4);
            Bt[ng + q * 4 + 0][j2] = f2b(f.x);
            Bt[ng + q * 4 + 1][j2] = f2b(f.y);
            Bt[ng + q * 4 + 2][j2] = f2b(f.z);
            Bt[ng + q * 4 + 3][j2] = f2b(f.w);
        }
    }
    __syncthreads();

    f32x4 acc[4] = {};
    #pragma unroll
    for (int kt = 0; kt < 2; kt++) {
        int k = kt * 32 + quad * 8;
        bf16x8 af = *(const bf16x8*)&Xw[wave * 16 + (lane & 15)][k];
        #pragma unroll
        for (int ni = 0; ni < 4; ni++) {
            bf16x8 bf = *(const bf16x8*)&Bt[ni * 16 + (lane & 15)][k];
            acc[ni] = __builtin_amdgcn_mfma_f32_16x16x32_bf16(af, bf, acc[ni], 0, 0, 0);
        }
    }

    ushort* out = cs + ((size_t)id * NCHUNK + c) * HD * DSTATE;
    #pragma unroll
    for (int ni = 0; ni < 4; ni++) {
        #pragma unroll
        for (int j = 0; j < 4; j++) {
            int p = wave * 16 + quad * 4 + j;
            int n = ni * 16 + (lane & 15);
            out[(size_t)p * DSTATE + n] = f2b(acc[ni][j]);
        }
    }
}

// ---------------------------------------------------------------------------
// Stitch: H_{c+1} = S_c + exp(sum ldA) * H_c (in place -> chunk-start H_c)
// ---------------------------------------------------------------------------
__global__ __launch_bounds__(256) void stitch_k(
    const float* __restrict__ ldT, ushort* __restrict__ cs)
{
    int id = blockIdx.x;
    int tid = threadIdx.x;
    __shared__ float red[256];
    __shared__ float dec[NCHUNK];

    float4 d4 = *(const float4*)(ldT + (size_t)id * SEQ + tid * 4);
    red[tid] = d4.x + d4.y + d4.z + d4.w;
    __syncthreads();
    if (tid < NCHUNK) {
        float s = 0.f;
        #pragma unroll
        for (int i = 0; i < 16; i++) s += red[tid * 16 + i];
        dec[tid] = expf(s);
    }
    __syncthreads();

    int p = tid >> 2, n0 = (tid & 3) * 16;
    ushort* ptr = cs + (size_t)id * NCHUNK * HD * DSTATE + p * DSTATE + n0;

    float st[16];
    #pragma unroll
    for (int i = 0; i < 16; i++) st[i] = 0.f;

    for (int c = 0; c < NCHUNK; c++) {
        ushort* row = ptr + (size_t)c * HD * DSTATE;
        float tmp[16];
        #pragma unroll
        for (int i = 0; i < 16; i++) tmp[i] = b2f(row[i]);
        #pragma unroll
        for (int i = 0; i < 16; i++) row[i] = f2b(st[i]);
        float d = dec[c];
        #pragma unroll
        for (int i = 0; i < 16; i++) st[i] = fmaf(d, st[i], tmp[i]);
    }
}

// ---------------------------------------------------------------------------
// ssd_k: intra-chunk SSD matmul + seed + D*x. Block remap via idmap128.
// ---------------------------------------------------------------------------
__global__ __launch_bounds__(256) void ssd_k(
    const float* __restrict__ Bq, const float* __restrict__ Cq,
    const float* __restrict__ dtT, const float* __restrict__ ldT,
    const ushort* __restrict__ xsq, const ushort* __restrict__ cs,
    const float* __restrict__ D0, const float* __restrict__ D1,
    ushort* __restrict__ yout)
{
    int id = idmap128(blockIdx.x);
    int dir = id >> 6, h = id & 31;
    int c = blockIdx.y;
    int tid = threadIdx.x;
    int wave = tid >> 6, lane = tid & 63;
    int quad = lane >> 4;
    int base = (id >> 5) << 10;
    int l0 = c * QC;

    __shared__ float cum[QC], dts[QC];
    __shared__ ushort Ms[64][72];
    __shared__ ushort Xb[64][80];

    {
        int j = tid >> 2, p0 = (tid & 3) * 16;
        const ushort* xrow = xsq + (size_t)(base + l0 + j) * DINNER + h * HD + p0;
        #pragma unroll
        for (int q = 0; q < 4; q++) {
            ushort4 xv = *(const ushort4*)(xrow + q * 4);
            Xb[p0 + q * 4 + 0][j] = xv.x;
            Xb[p0 + q * 4 + 1][j] = xv.y;
            Xb[p0 + q * 4 + 2][j] = xv.z;
            Xb[p0 + q * 4 + 3][j] = xv.w;
        }
    }
    if (tid < 64) {
        float ld = ldT[(size_t)id * SEQ + l0 + tid];
        #pragma unroll
        for (int st = 1; st < 64; st <<= 1) {
            float o = __shfl_up(ld, st);
            if (tid >= st) ld += o;
        }
        cum[tid] = ld;
        dts[tid] = dtT[(size_t)id * SEQ + l0 + tid];
    }

    f32x4 sacc[4] = {};
    #pragma unroll
    for (int kt = 0; kt < 2; kt++) {
        int k = kt * 32 + quad * 8;
        const float* cp = Cq + (size_t)(base + l0 + wave * 16 + (lane & 15)) * DSTATE + k;
        bf16x8 af = pack8(*(const float4*)cp, *(const float4*)(cp + 4));
        #pragma unroll
        for (int ni = 0; ni < 4; ni++) {
            const float* bp = Bq + (size_t)(base + l0 + ni * 16 + (lane & 15)) * DSTATE + k;
            bf16x8 bf = pack8(*(const float4*)bp, *(const float4*)(bp + 4));
            sacc[ni] = __builtin_amdgcn_mfma_f32_16x16x32_bf16(af, bf, sacc[ni], 0, 0, 0);
        }
    }
    __syncthreads();

    #pragma unroll
    for (int ni = 0; ni < 4; ni++) {
        int j = ni * 16 + (lane & 15);
        float cj = cum[j], dj = dts[j];
        #pragma unroll
        for (int r = 0; r < 4; r++) {
            int l = wave * 16 + quad * 4 + r;
            float v = 0.f;
            if (l >= j) v = expf(cum[l] - cj) * dj * sacc[ni][r];
            Ms[l][j] = f2b(v);
        }
    }
    __syncthreads();

    f32x4 acc[4] = {};
    #pragma unroll
    for (int kt = 0; kt < 2; kt++) {
        int k = kt * 32 + quad * 8;
        bf16x8 af = *(const bf16x8*)&Ms[wave * 16 + (lane & 15)][k];
        #pragma unroll
        for (int ni = 0; ni < 4; ni++) {
            bf16x8 bf = *(const bf16x8*)&Xb[ni * 16 + (lane & 15)][k];
            acc[ni] = __builtin_amdgcn_mfma_f32_16x16x32_bf16(af, bf, acc[ni], 0, 0, 0);
        }
    }
    const ushort* Hrow = cs + ((size_t)id * NCHUNK + c) * HD * DSTATE;
    {
        float cl = expf(cum[wave * 16 + (lane & 15)]);
        #pragma unroll
        for (int kt = 0; kt < 2; kt++) {
            int k = kt * 32 + quad * 8;
            const float* cp = Cq + (size_t)(base + l0 + wave * 16 + (lane & 15)) * DSTATE + k;
            float4 c0 = *(const float4*)cp;
            float4 c1 = *(const float4*)(cp + 4);
            float4 s0 = {c0.x * cl, c0.y * cl, c0.z * cl, c0.w * cl};
            float4 s1 = {c1.x * cl, c1.y * cl, c1.z * cl, c1.w * cl};
            bf16x8 af = pack8(s0, s1);
            #pragma unroll
            for (int ni = 0; ni < 4; ni++) {
                bf16x8 bf = *(const bf16x8*)(Hrow + (size_t)(ni * 16 + (lane & 15)) * DSTATE + k);
                acc[ni] = __builtin_amdgcn_mfma_f32_16x16x32_bf16(af, bf, acc[ni], 0, 0, 0);
            }
        }
    }

    float Dv = (dir ? D1 : D0)[h];
    int lb = wave * 16 + quad * 4;
    #pragma unroll
    for (int ni = 0; ni < 4; ni++) {
        int p = ni * 16 + (lane & 15);
        ushort4 x4 = *(const ushort4*)&Xb[p][lb];
        float xv[4] = { b2f(x4.x), b2f(x4.y), b2f(x4.z), b2f(x4.w) };
        #pragma unroll
        for (int r = 0; r < 4; r++) {
            int l = lb + r;
            yout[(size_t)(base + l0 + l) * DPROJ + 2048 + h * HD + p] =
                f2b(acc[ni][r] + Dv * xv[r]);
        }
    }
}

// ---------------------------------------------------------------------------
// gated RMSNorm (blocks 0..4095) fused with out_proj/final weight conversion
// (blocks 4096..10239; wo/wp live in the CS region — disjoint from zx).
// ---------------------------------------------------------------------------
__global__ __launch_bounds__(256) void grms_cvt_k(
    const ushort* __restrict__ zx,
    const float* __restrict__ rw0, const float* __restrict__ rw1,
    ushort* __restrict__ yn,
    const float* __restrict__ fow, const float* __restrict__ bow,
    const float* __restrict__ pw,
    ushort* __restrict__ wo, ushort* __restrict__ wp)
{
    int blk = blockIdx.x;
    int tid = threadIdx.x;
    if (blk >= 4096) {
        int b = blk - 4096;                 // 0..6143, rows of 1024 floats
        const float* s; ushort* d; size_t off;
        if (b < 2048)      { s = fow; d = wo;                           off = (size_t)b * 1024; }
        else if (b < 4096) { s = bow; d = wo + (size_t)DMODEL * DINNER; off = (size_t)(b - 2048) * 1024; }
        else               { s = pw;  d = wp;                           off = (size_t)(b - 4096) * 1024; }
        size_t i = off + tid * 4;
        float4 f = *(const float4*)(s + i);
        ushort4 u;
        u.x = f2b(f.x); u.y = f2b(f.y); u.z = f2b(f.z); u.w = f2b(f.w);
        *(ushort4*)(d + i) = u;
        return;
    }
    int id = blk;
    int dir = id >> 11;
    const float* rw = dir ? rw1 : rw0;
    int c0 = tid * 8;
    ushort zv[8], yv[8];
    *(uint4*)zv = *(const uint4*)&zx[(size_t)id * DPROJ + c0];
    *(uint4*)yv = *(const uint4*)&zx[(size_t)id * DPROJ + 2048 + c0];
    float g[8];
    float ss = 0.f;
    #pragma unroll
    for (int i = 0; i < 8; i++) {
        float z = b2f(zv[i]);
        float v = b2f(yv[i]) * (z / (1.f + expf(-z)));
        g[i] = v;
        ss += v * v;
    }
    for (int o = 32; o; o >>= 1) ss += __shfl_down(ss, o);
    __shared__ float t4[4];
    if ((tid & 63) == 0) t4[tid >> 6] = ss;
    __syncthreads();
    ss = t4[0] + t4[1] + t4[2] + t4[3];
    float sc = rsqrtf(ss * (1.f / DINNER) + 1e-5f);
    ushort u[8];
    #pragma unroll
    for (int i = 0; i < 8; i++) u[i] = f2b(g[i] * sc * rw[c0 + i]);
    *(uint4*)&yn[(size_t)id * DINNER + c0] = *(uint4*)u;
}

// ---------------------------------------------------------------------------
// LayerNorm -> fp32 out — vectorized: one float4/thread.
// ---------------------------------------------------------------------------
__global__ __launch_bounds__(256) void ln_k(
    const float* __restrict__ h, const float* __restrict__ lw,
    const float* __restrict__ lb, float* __restrict__ out)
{
    int m = blockIdx.x;
    int tid = threadIdx.x;
    int c = tid * 4;
    float4 v = *(const float4*)&h[(size_t)m * DMODEL + c];
    float s  = v.x + v.y + v.z + v.w;
    float s2 = v.x * v.x + v.y * v.y + v.z * v.z + v.w * v.w;
    for (int o = 32; o; o >>= 1) { s += __shfl_down(s, o); s2 += __shfl_down(s2, o); }
    __shared__ float ts[4], ts2[4];
    if ((tid & 63) == 0) { ts[tid >> 6] = s; ts2[tid >> 6] = s2; }
    __syncthreads();
    s  = ts[0] + ts[1] + ts[2] + ts[3];
    s2 = ts2[0] + ts2[1] + ts2[2] + ts2[3];
    float mu  = s * (1.f / DMODEL);
    float var = s2 * (1.f / DMODEL) - mu * mu;
    float sc  = rsqrtf(var + 1e-5f);
    float4 w4 = *(const float4*)&lw[c];
    float4 b4 = *(const float4*)&lb[c];
    float4 o4;
    o4.x = (v.x - mu) * sc * w4.x + b4.x;
    o4.y = (v.y - mu) * sc * w4.y + b4.y;
    o4.z = (v.z - mu) * sc * w4.z + b4.z;
    o4.w = (v.w - mu) * sc * w4.w + b4.w;
    *(float4*)&out[(size_t)m * DMODEL + c] = o4;
}

extern "C" void kernel_launch(void* const* d_in, const int* in_sizes, int n_in,
                              void* d_out, int out_size, void* d_ws, size_t ws_size,
                              hipStream_t stream)
{
    const float* x     = (const float*)d_in[0];
    const float* f_inw = (const float*)d_in[1];
    const float* f_cw  = (const float*)d_in[2];
    const float* f_cb  = (const float*)d_in[3];
    const float* f_dtb = (const float*)d_in[4];
    const float* f_al  = (const float*)d_in[5];
    const float* f_Dp  = (const float*)d_in[6];
    const float* f_rw  = (const float*)d_in[7];
    const float* f_ow  = (const float*)d_in[8];
    const float* b_inw = (const float*)d_in[9];
    const float* b_cw  = (const float*)d_in[10];
    const float* b_cb  = (const float*)d_in[11];
    const float* b_dtb = (const float*)d_in[12];
    const float* b_al  = (const float*)d_in[13];
    const float* b_Dp  = (const float*)d_in[14];
    const float* b_rw  = (const float*)d_in[15];
    const float* b_ow  = (const float*)d_in[16];
    const float* projw = (const float*)d_in[17];
    const float* projb = (const float*)d_in[18];
    const float* lnw   = (const float*)d_in[19];
    const float* lnb   = (const float*)d_in[20];

    char* ws = (char*)d_ws;
    ushort* zx  = (ushort*)(ws + OFF_ZX);
    ushort* xs  = (ushort*)(ws + OFF_XS);
    float*  Bq  = (float*)(ws + OFF_BB);
    float*  Cq  = (float*)(ws + OFF_CC);
    float*  dtq = (float*)(ws + OFF_DT);
    float*  ldq = (float*)(ws + OFF_DA);
    float*  dtr = (float*)(ws + OFF_DR);
    ushort* wbf = (ushort*)(ws + OFF_CS);
    ushort* cs  = (ushort*)(ws + OFF_CS);
    ushort* xbf = (ushort*)(ws + OFF_XS);   // x bf16, dead once conv_k writes xs
    ushort* yn  = (ushort*)(ws + OFF_XS);   // aliases xs (dead after ssd)
    ushort* dd  = (ushort*)(ws + OFF_DD);   // aliases zx (dead after grms)
    float*  hb  = (float*)(ws + OFF_H);
    ushort* wo  = (ushort*)(ws + OFF_WO);   // CS region (dead after ssd)
    ushort* wp  = (ushort*)(ws + OFF_WP);

    // K0: bf16 conversions needed before in_proj (one launch)
    cvt3_k<<<dim3(2 * DPROJ + MROWS), 256, 0, stream>>>(
        f_inw, b_inw, x, wbf, wbf + (size_t)DPROJ * DMODEL, xbf, DPROJ, DPROJ);

    // K1: in_proj, N=4256, K=1024; BM=256, BN=128, BK=64, 512 threads
    gemm_in_k<<<dim3((DPROJ + 127) / 128, MROWS / 256, 2), 512, 0, stream>>>(
        xbf, wbf, (size_t)DPROJ * DMODEL, zx, dtr, DPROJ, DMODEL);

    // K2: conv + activations (overwrites xbf region with xs)
    conv_k<<<dim3(2 * MROWS), 256, 0, stream>>>(
        zx, dtr, f_cw, f_cb, b_cw, b_cb, f_dtb, f_al, b_dtb, b_al,
        xs, Bq, Cq, dtq, ldq);

    // K3: chunked SSD (states / stitch / intra-chunk matmul)
    states_k<<<dim3(128, NCHUNK), 256, 0, stream>>>(Bq, dtq, ldq, xs, cs);
    stitch_k<<<dim3(128), 256, 0, stream>>>(ldq, cs);
    ssd_k<<<dim3(128, NCHUNK), 256, 0, stream>>>(
        Bq, Cq, dtq, ldq, xs, cs, f_Dp, b_Dp, zx);

    // K4: gated RMSNorm + weight conversions (CS region now dead) fused
    grms_cvt_k<<<dim3(4096 + 3 * MROWS), 256, 0, stream>>>(
        zx, f_rw, b_rw, yn, f_ow, b_ow, projw, wo, wp);

    // K5: out_proj, N=1024, K=2048, BN=64, BK=128; packs [dou0|flip(dou1)] into dd
    gemm_k<1, 64, 128><<<dim3(DMODEL / 64, MROWS / 128, 2), 256, 0, stream>>>(
        yn, wo, (size_t)DMODEL * DINNER, (void*)dd, nullptr, nullptr, nullptr,
        DMODEL, DINNER);

    // K6: final proj + residual + bias, N=1024, K=2048, BN=64, BK=128 (fp32 out)
    gemm_k<2, 64, 128><<<dim3(DMODEL / 64, MROWS / 128, 1), 256, 0, stream>>>(
        dd, wp, 0, (void*)hb, x, projb, nullptr, DMODEL, DINNER);

    // K7: LayerNorm -> fp32 out
    ln_k<<<dim3(MROWS), 256, 0, stream>>>(hb, lnw, lnb, (float*)d_out);
}